// Round 2
// baseline (342.506 us; speedup 1.0000x reference)
//
#include <hip/hip_runtime.h>

typedef float  f32x4 __attribute__((ext_vector_type(4)));
typedef short  s16x8 __attribute__((ext_vector_type(8)));
typedef unsigned short u16;

// ---- workspace layout (bytes) ----
#define OFF_E     0ULL            // e  bf16 [65536][128]            16 MiB
#define OFF_ET    16777216ULL     // eT bf16 [8][128][8192]          16 MiB
#define OFF_EPART 33554432ULL     // Epart f32 [16][8][512][128]     32 MiB
#define OFF_XT    67108864ULL     // xT bf16 [8][512][8192]          64 MiB
#define OFF_GT    134217728ULL    // Gt bf16 [8][512][128]            1 MiB
#define OFF_WT    135266304ULL    // Wt bf16 [128][512]             128 KiB
#define OFF_ZP    135397376ULL    // zpart f32 [512][128]           256 KiB
#define OFF_RZ2   135659520ULL    // rz2 f32 [1024]                   4 KiB
#define WS_NEED   135663616ULL

__device__ __forceinline__ u16 f2bf(float f) {
  unsigned u = __float_as_uint(f);
  return (u16)((u + 0x8000u) >> 16);          // round-half-up to bf16
}
__device__ __forceinline__ unsigned pack2(float a, float b) {
  unsigned ua = __float_as_uint(a), ub = __float_as_uint(b);
  return ((ua + 0x8000u) >> 16) | ((ub + 0x8000u) & 0xffff0000u);
}

// ------------------------------------------------------------------
// k_wt: Wt[h][c] = bf16(W[c][h])
__global__ __launch_bounds__(256) void k_wt(const float* __restrict__ W,
                                            u16* __restrict__ Wt) {
  int idx = blockIdx.x * 256 + threadIdx.x;    // 65536 total
  int h = idx & 127, c = idx >> 7;
  Wt[h * 512 + c] = f2bf(W[c * 128 + h]);
}

// ------------------------------------------------------------------
// k_xT: xT[b][c][s] = bf16(x[b][s][c]). No LDS: each thread packs 4
// consecutive s for fixed c into one b64 store (coalesced 128B/16 lanes).
__global__ __launch_bounds__(256) void k_xT(const float* __restrict__ x,
                                            u16* __restrict__ xT) {
  const int tid = threadIdx.x;
  const int sc = blockIdx.x;      // 0..127: 64-row s-chunk
  const int b  = blockIdx.y;
  const int rq = tid & 15;        // s = 4*rq .. 4*rq+3 within chunk
  const int cseg = tid >> 4;      // 0..15: c base cseg*32
  const int s0 = sc * 64 + rq * 4;
#pragma unroll
  for (int p = 0; p < 2; ++p) {
    const int c0 = cseg * 32 + p * 16;
    const float* src = x + ((size_t)(b * 8192 + s0) * 512 + c0);
    f32x4 r0[4], r1[4], r2[4], r3[4];
#pragma unroll
    for (int j = 0; j < 4; ++j) {
      r0[j] = *(const f32x4*)(src + j * 4);
      r1[j] = *(const f32x4*)(src + 512 + j * 4);
      r2[j] = *(const f32x4*)(src + 1024 + j * 4);
      r3[j] = *(const f32x4*)(src + 1536 + j * 4);
    }
#pragma unroll
    for (int j = 0; j < 4; ++j)
#pragma unroll
      for (int i = 0; i < 4; ++i) {
        const int c = c0 + j * 4 + i;
        unsigned lo = pack2(r0[j][i], r1[j][i]);
        unsigned hi = pack2(r2[j][i], r3[j][i]);
        unsigned long long vv = (unsigned long long)lo | ((unsigned long long)hi << 32);
        *(unsigned long long*)(xT + ((size_t)(b * 512 + c) * 8192 + s0)) = vv;
      }
  }
}

// ------------------------------------------------------------------
// k_logits_e: per 128-row tile: logits = x@Wt (bf16 MFMA), then
// e = exp(logits) -> writes e (natural) + eT (transposed) bf16, and
// per-column partial sums of e (zpart).   [unchanged — verified]
__global__ __launch_bounds__(256) void k_logits_e(
    const float* __restrict__ x, const u16* __restrict__ Wt,
    u16* __restrict__ e, u16* __restrict__ eT, float* __restrict__ zpart) {
  __shared__ __align__(16) u16 sm[128 * 128];
  __shared__ float zs[512];
  u16* lA = sm;
  u16* lB = sm + 8192;
  const int tid = threadIdx.x;
  const int lane = tid & 63, wave = tid >> 6;
  const int l15 = lane & 15, quad = lane >> 4;
  const int mt = blockIdx.x;                   // 0..511
  const int rowBase = mt << 7;

  f32x4 acc[2][8];
#pragma unroll
  for (int i = 0; i < 2; ++i)
#pragma unroll
    for (int j = 0; j < 8; ++j) acc[i][j] = (f32x4){0.f, 0.f, 0.f, 0.f};

  for (int kt = 0; kt < 8; ++kt) {
    const int k0 = kt << 6;
    if (kt) __syncthreads();
    {
      const int q = tid & 3, rb = tid >> 2;
#pragma unroll
      for (int rep = 0; rep < 2; ++rep) {
        const int r = rb + rep * 64;
        const float* src = x + (size_t)(rowBase + r) * 512 + k0 + q * 4;
#pragma unroll
        for (int j = 0; j < 4; ++j) {
          f32x4 v = *(const f32x4*)(src + j * 16);
          const int chunk = (2 * j + (q >> 1)) ^ (r & 7);
          unsigned* dst = (unsigned*)&lA[r * 64 + chunk * 8 + (q & 1) * 4];
          dst[0] = pack2(v[0], v[1]);
          dst[1] = pack2(v[2], v[3]);
        }
      }
    }
    {
      const int oct = tid & 7, rb = tid >> 3;
#pragma unroll
      for (int rep = 0; rep < 4; ++rep) {
        const int r = rb + rep * 32;
        s16x8 v = *(const s16x8*)(Wt + r * 512 + k0 + oct * 8);
        *(s16x8*)&lB[r * 64 + ((oct ^ (r & 7)) * 8)] = v;
      }
    }
    __syncthreads();
#pragma unroll
    for (int kk = 0; kk < 2; ++kk) {
      s16x8 af[2], bf[8];
#pragma unroll
      for (int i = 0; i < 2; ++i) {
        const int r = wave * 32 + i * 16 + l15;
        af[i] = *(const s16x8*)&lA[r * 64 + (((kk * 4 + quad) ^ (r & 7)) * 8)];
      }
#pragma unroll
      for (int j = 0; j < 8; ++j) {
        const int r = j * 16 + l15;
        bf[j] = *(const s16x8*)&lB[r * 64 + (((kk * 4 + quad) ^ (r & 7)) * 8)];
      }
#pragma unroll
      for (int i = 0; i < 2; ++i)
#pragma unroll
        for (int j = 0; j < 8; ++j)
          acc[i][j] = __builtin_amdgcn_mfma_f32_16x16x32_bf16(af[i], bf[j], acc[i][j], 0, 0, 0);
    }
  }

  float ex[2][8][4];
  float cs[8];
#pragma unroll
  for (int j = 0; j < 8; ++j) cs[j] = 0.f;
#pragma unroll
  for (int i = 0; i < 2; ++i)
#pragma unroll
    for (int j = 0; j < 8; ++j)
#pragma unroll
      for (int rr = 0; rr < 4; ++rr) {
        float l = acc[i][j][rr];
        l = fminf(fmaxf(l, -30.f), 30.f);
        float t = __expf(l);
        ex[i][j][rr] = t;
        cs[j] += t;
      }
#pragma unroll
  for (int j = 0; j < 8; ++j) {
    cs[j] += __shfl_xor(cs[j], 16);
    cs[j] += __shfl_xor(cs[j], 32);
  }
  if (quad == 0) {
#pragma unroll
    for (int j = 0; j < 8; ++j) zs[wave * 128 + j * 16 + l15] = cs[j];
  }
  __syncthreads();

#pragma unroll
  for (int i = 0; i < 2; ++i)
#pragma unroll
    for (int j = 0; j < 8; ++j)
#pragma unroll
      for (int rr = 0; rr < 4; ++rr) {
        int s = wave * 32 + i * 16 + quad * 4 + rr;
        int h = j * 16 + l15;
        sm[s * 128 + (((h >> 3) ^ (s & 15)) * 8) + (h & 7)] = f2bf(ex[i][j][rr]);
      }
  if (tid < 128)
    zpart[mt * 128 + tid] = zs[tid] + zs[128 + tid] + zs[256 + tid] + zs[384 + tid];
  __syncthreads();

  {
    int s = tid >> 1;
#pragma unroll
    for (int i = 0; i < 8; ++i) {
      int c = (tid & 1) * 8 + i;
      s16x8 v = *(const s16x8*)&sm[s * 128 + ((c ^ (s & 15)) * 8)];
      *(s16x8*)(e + (size_t)(rowBase + s) * 128 + c * 8) = v;
    }
  }
  {
    int ck = tid & 15, hb = tid >> 4;
    int b = mt >> 6;
    int sBase = (mt & 63) << 7;
#pragma unroll
    for (int pass = 0; pass < 8; ++pass) {
      int h = hb + pass * 16;
      s16x8 v;
#pragma unroll
      for (int j = 0; j < 8; ++j) {
        int s = ck * 8 + j;
        v[j] = (short)sm[s * 128 + (((h >> 3) ^ (s & 15)) * 8) + (h & 7)];
      }
      *(s16x8*)(eT + (size_t)(b * 128 + h) * 8192 + sBase + ck * 8) = v;
    }
  }
}

// ------------------------------------------------------------------
// k_zmerge: Z per (b,h), store 1/Z^2
__global__ __launch_bounds__(256) void k_zmerge(const float* __restrict__ zpart,
                                                float* __restrict__ rz2) {
  int gid = blockIdx.x * 256 + threadIdx.x;  // 0..1023
  int b = gid >> 7, h = gid & 127;
  float z = 0.f;
  for (int i = 0; i < 64; ++i) z += zpart[(b * 64 + i) * 128 + h];
  rz2[gid] = 1.0f / (z * z);
}

// ------------------------------------------------------------------
// k_E: Eparts in [c][h] orientation: E^T[c][h] = sum_s xT[c][s]*eT[h][s].
// Both operands natural k-major -> straight b128 staging, verified (row&7)
// swizzle, conflict-free fragment reads. Tile 128c x 128h, split-K kc=16.
__global__ __launch_bounds__(256) void k_E(const u16* __restrict__ xT,
                                           const u16* __restrict__ eT,
                                           float* __restrict__ Epart) {
  __shared__ __align__(16) u16 lA[128 * 64];   // xT rows (m=c)  16 KiB
  __shared__ __align__(16) u16 lB[128 * 64];   // eT rows (n=h)  16 KiB
  const int tid = threadIdx.x;
  const int lane = tid & 63, wave = tid >> 6;
  const int l15 = lane & 15, quad = lane >> 4;
  const int nt = blockIdx.x;   // c band 0..3 (128 wide)
  const int b = blockIdx.y;
  const int kc = blockIdx.z;   // 0..15: 512-s chunk

  f32x4 acc[2][8];
#pragma unroll
  for (int i = 0; i < 2; ++i)
#pragma unroll
    for (int j = 0; j < 8; ++j) acc[i][j] = (f32x4){0.f, 0.f, 0.f, 0.f};

  for (int kt = 0; kt < 8; ++kt) {
    const int sb = kc * 512 + kt * 64;
    if (kt) __syncthreads();
    {
      const int oct = tid & 7, rb = tid >> 3;
#pragma unroll
      for (int rep = 0; rep < 4; ++rep) {
        const int r = rb + rep * 32;
        s16x8 va = *(const s16x8*)(xT + (size_t)(b * 512 + nt * 128 + r) * 8192 + sb + oct * 8);
        *(s16x8*)&lA[r * 64 + ((oct ^ (r & 7)) * 8)] = va;
        s16x8 vb = *(const s16x8*)(eT + (size_t)(b * 128 + r) * 8192 + sb + oct * 8);
        *(s16x8*)&lB[r * 64 + ((oct ^ (r & 7)) * 8)] = vb;
      }
    }
    __syncthreads();
#pragma unroll
    for (int kk = 0; kk < 2; ++kk) {
      s16x8 af[2], bf[8];
#pragma unroll
      for (int i = 0; i < 2; ++i) {
        const int r = wave * 32 + i * 16 + l15;
        af[i] = *(const s16x8*)&lA[r * 64 + (((kk * 4 + quad) ^ (r & 7)) * 8)];
      }
#pragma unroll
      for (int j = 0; j < 8; ++j) {
        const int n = j * 16 + l15;
        bf[j] = *(const s16x8*)&lB[n * 64 + (((kk * 4 + quad) ^ (n & 7)) * 8)];
      }
#pragma unroll
      for (int i = 0; i < 2; ++i)
#pragma unroll
        for (int j = 0; j < 8; ++j)
          acc[i][j] = __builtin_amdgcn_mfma_f32_16x16x32_bf16(af[i], bf[j], acc[i][j], 0, 0, 0);
    }
  }
  float* dst = Epart + ((size_t)(kc * 8 + b) * 512 + nt * 128) * 128;
#pragma unroll
  for (int i = 0; i < 2; ++i)
#pragma unroll
    for (int j = 0; j < 8; ++j)
#pragma unroll
      for (int rr = 0; rr < 4; ++rr) {
        int c = wave * 32 + i * 16 + quad * 4 + rr;
        int h = j * 16 + l15;
        dst[(size_t)c * 128 + h] = acc[i][j][rr];
      }
}

// ------------------------------------------------------------------
// k_G: Gt[b][c][h] = bf16( (sum_p Epart[p][b][c][h]) * rz2[b][h] )
// fully vectorized: f32x4 reads, b128 bf16 stores.
__global__ __launch_bounds__(256) void k_G(const float* __restrict__ Epart,
                                           const float* __restrict__ rz2,
                                           u16* __restrict__ Gt) {
  int idx = blockIdx.x * 256 + threadIdx.x;  // 65536 threads, 8 h each
  int h8 = idx & 15, c = (idx >> 4) & 511, b = idx >> 13;
  f32x4 s0 = {0.f, 0.f, 0.f, 0.f}, s1 = {0.f, 0.f, 0.f, 0.f};
#pragma unroll
  for (int p = 0; p < 16; ++p) {
    const float* src = Epart + (((size_t)(p * 8 + b) * 512 + c) * 128 + h8 * 8);
    s0 += *(const f32x4*)src;
    s1 += *(const f32x4*)(src + 4);
  }
  const float* rz = rz2 + b * 128 + h8 * 8;
  f32x4 z0 = *(const f32x4*)rz;
  f32x4 z1 = *(const f32x4*)(rz + 4);
  unsigned ov[4];
  ov[0] = pack2(s0[0] * z0[0], s0[1] * z0[1]);
  ov[1] = pack2(s0[2] * z0[2], s0[3] * z0[3]);
  ov[2] = pack2(s1[0] * z1[0], s1[1] * z1[1]);
  ov[3] = pack2(s1[2] * z1[2], s1[3] * z1[3]);
  *(s16x8*)(Gt + ((size_t)(b * 512 + c) * 128 + h8 * 8)) = *(s16x8*)ov;
}

// ------------------------------------------------------------------
// k_out: out[s][c] = e[s][:] @ G[:, c]  (A = e natural, B = Gt natural)
// [unchanged — verified]
__global__ __launch_bounds__(256) void k_out(const u16* __restrict__ e,
                                             const u16* __restrict__ Gt,
                                             float* __restrict__ out) {
  __shared__ __align__(16) u16 lA[128 * 128];
  __shared__ __align__(16) u16 lB[128 * 128];
  const int tid = threadIdx.x;
  const int lane = tid & 63, wave = tid >> 6;
  const int l15 = lane & 15, quad = lane >> 4;
  const int st = blockIdx.x;
  const int b = blockIdx.y;

  {
    const int hx = tid & 15, rb = tid >> 4;
#pragma unroll
    for (int pass = 0; pass < 8; ++pass) {
      const int r = rb + pass * 16;
      s16x8 v = *(const s16x8*)(e + (size_t)(b * 8192 + st * 128 + r) * 128 + hx * 8);
      *(s16x8*)&lA[r * 128 + ((hx ^ (r & 15)) * 8)] = v;
    }
  }
  for (int ct = 0; ct < 4; ++ct) {
    __syncthreads();
    {
      const int hx = tid & 15, rb = tid >> 4;
#pragma unroll
      for (int pass = 0; pass < 8; ++pass) {
        const int r = rb + pass * 16;
        s16x8 v = *(const s16x8*)(Gt + (size_t)(b * 512 + ct * 128 + r) * 128 + hx * 8);
        *(s16x8*)&lB[r * 128 + ((hx ^ (r & 15)) * 8)] = v;
      }
    }
    __syncthreads();
    f32x4 acc[2][8];
#pragma unroll
    for (int i = 0; i < 2; ++i)
#pragma unroll
      for (int j = 0; j < 8; ++j) acc[i][j] = (f32x4){0.f, 0.f, 0.f, 0.f};
#pragma unroll
    for (int kk = 0; kk < 4; ++kk) {
      s16x8 af[2], bf[8];
#pragma unroll
      for (int i = 0; i < 2; ++i) {
        const int r = wave * 32 + i * 16 + l15;
        af[i] = *(const s16x8*)&lA[r * 128 + (((kk * 4 + quad) ^ (r & 15)) * 8)];
      }
#pragma unroll
      for (int j = 0; j < 8; ++j) {
        const int n = j * 16 + l15;
        bf[j] = *(const s16x8*)&lB[n * 128 + (((kk * 4 + quad) ^ (n & 15)) * 8)];
      }
#pragma unroll
      for (int i = 0; i < 2; ++i)
#pragma unroll
        for (int j = 0; j < 8; ++j)
          acc[i][j] = __builtin_amdgcn_mfma_f32_16x16x32_bf16(af[i], bf[j], acc[i][j], 0, 0, 0);
    }
#pragma unroll
    for (int i = 0; i < 2; ++i)
#pragma unroll
      for (int j = 0; j < 8; ++j)
#pragma unroll
        for (int rr = 0; rr < 4; ++rr) {
          int s = wave * 32 + i * 16 + quad * 4 + rr;
          int c = j * 16 + l15;
          out[(size_t)(b * 8192 + st * 128 + s) * 512 + ct * 128 + c] = acc[i][j][rr];
        }
  }
}

// ------------------------------------------------------------------
extern "C" void kernel_launch(void* const* d_in, const int* in_sizes, int n_in,
                              void* d_out, int out_size, void* d_ws, size_t ws_size,
                              hipStream_t stream) {
  if (ws_size < (size_t)WS_NEED) return;  // need ~129.4 MiB scratch
  const float* x = (const float*)d_in[0];
  const float* W = (const float*)d_in[1];
  float* out = (float*)d_out;
  char* ws = (char*)d_ws;
  u16* e = (u16*)(ws + OFF_E);
  u16* eT = (u16*)(ws + OFF_ET);
  float* Epart = (float*)(ws + OFF_EPART);
  u16* xT = (u16*)(ws + OFF_XT);
  u16* Gt = (u16*)(ws + OFF_GT);
  u16* Wt = (u16*)(ws + OFF_WT);
  float* zpart = (float*)(ws + OFF_ZP);
  float* rz2 = (float*)(ws + OFF_RZ2);

  k_wt<<<256, 256, 0, stream>>>(W, Wt);
  k_xT<<<dim3(128, 8), 256, 0, stream>>>(x, xT);
  k_logits_e<<<512, 256, 0, stream>>>(x, Wt, e, eT, zpart);
  k_zmerge<<<4, 256, 0, stream>>>(zpart, rz2);
  k_E<<<dim3(4, 8, 16), 256, 0, stream>>>(xT, eT, Epart);
  k_G<<<256, 256, 0, stream>>>(Epart, rz2, Gt);
  k_out<<<dim3(64, 8), 256, 0, stream>>>(e, Gt, out);
}

// Round 3
// 301.836 us; speedup vs baseline: 1.1347x; 1.1347x over previous
//
#include <hip/hip_runtime.h>

typedef float  f32x4 __attribute__((ext_vector_type(4)));
typedef short  s16x8 __attribute__((ext_vector_type(8)));
typedef unsigned short u16;

// ---- workspace layout (bytes) ----
#define OFF_E     0ULL            // e  bf16 [65536][128]            16 MiB
#define OFF_ET    16777216ULL     // eT bf16 [8][128][8192]          16 MiB
#define OFF_EPART 33554432ULL     // Epart f32 [16][8][512][128]     32 MiB
#define OFF_GT    67108864ULL     // Gt bf16 [8][512][128]            1 MiB
#define OFF_WT    68157440ULL     // Wt bf16 [128][512]             128 KiB
#define OFF_ZP    68288512ULL     // zpart f32 [512][128]           256 KiB
#define OFF_RZ2   68550656ULL     // rz2 f32 [1024]                   4 KiB
#define WS_NEED   68554752ULL

__device__ __forceinline__ u16 f2bf(float f) {
  unsigned u = __float_as_uint(f);
  return (u16)((u + 0x8000u) >> 16);          // round-half-up to bf16
}
__device__ __forceinline__ unsigned pack2(float a, float b) {
  unsigned ua = __float_as_uint(a), ub = __float_as_uint(b);
  return ((ua + 0x8000u) >> 16) | ((ub + 0x8000u) & 0xffff0000u);
}

// ------------------------------------------------------------------
// k_wt: Wt[h][c] = bf16(W[c][h])
__global__ __launch_bounds__(256) void k_wt(const float* __restrict__ W,
                                            u16* __restrict__ Wt) {
  int idx = blockIdx.x * 256 + threadIdx.x;    // 65536 total
  int h = idx & 127, c = idx >> 7;
  Wt[h * 512 + c] = f2bf(W[c * 128 + h]);
}

// ------------------------------------------------------------------
// k_logits_e: per 128-row tile: logits = x@Wt (bf16 MFMA), then
// e = exp(logits) -> writes e (natural) + eT (transposed) bf16, and
// per-column partial sums of e (zpart).   [unchanged — verified]
__global__ __launch_bounds__(256) void k_logits_e(
    const float* __restrict__ x, const u16* __restrict__ Wt,
    u16* __restrict__ e, u16* __restrict__ eT, float* __restrict__ zpart) {
  __shared__ __align__(16) u16 sm[128 * 128];
  __shared__ float zs[512];
  u16* lA = sm;
  u16* lB = sm + 8192;
  const int tid = threadIdx.x;
  const int lane = tid & 63, wave = tid >> 6;
  const int l15 = lane & 15, quad = lane >> 4;
  const int mt = blockIdx.x;                   // 0..511
  const int rowBase = mt << 7;

  f32x4 acc[2][8];
#pragma unroll
  for (int i = 0; i < 2; ++i)
#pragma unroll
    for (int j = 0; j < 8; ++j) acc[i][j] = (f32x4){0.f, 0.f, 0.f, 0.f};

  for (int kt = 0; kt < 8; ++kt) {
    const int k0 = kt << 6;
    if (kt) __syncthreads();
    {
      const int q = tid & 3, rb = tid >> 2;
#pragma unroll
      for (int rep = 0; rep < 2; ++rep) {
        const int r = rb + rep * 64;
        const float* src = x + (size_t)(rowBase + r) * 512 + k0 + q * 4;
#pragma unroll
        for (int j = 0; j < 4; ++j) {
          f32x4 v = *(const f32x4*)(src + j * 16);
          const int chunk = (2 * j + (q >> 1)) ^ (r & 7);
          unsigned* dst = (unsigned*)&lA[r * 64 + chunk * 8 + (q & 1) * 4];
          dst[0] = pack2(v[0], v[1]);
          dst[1] = pack2(v[2], v[3]);
        }
      }
    }
    {
      const int oct = tid & 7, rb = tid >> 3;
#pragma unroll
      for (int rep = 0; rep < 4; ++rep) {
        const int r = rb + rep * 32;
        s16x8 v = *(const s16x8*)(Wt + r * 512 + k0 + oct * 8);
        *(s16x8*)&lB[r * 64 + ((oct ^ (r & 7)) * 8)] = v;
      }
    }
    __syncthreads();
#pragma unroll
    for (int kk = 0; kk < 2; ++kk) {
      s16x8 af[2], bf[8];
#pragma unroll
      for (int i = 0; i < 2; ++i) {
        const int r = wave * 32 + i * 16 + l15;
        af[i] = *(const s16x8*)&lA[r * 64 + (((kk * 4 + quad) ^ (r & 7)) * 8)];
      }
#pragma unroll
      for (int j = 0; j < 8; ++j) {
        const int r = j * 16 + l15;
        bf[j] = *(const s16x8*)&lB[r * 64 + (((kk * 4 + quad) ^ (r & 7)) * 8)];
      }
#pragma unroll
      for (int i = 0; i < 2; ++i)
#pragma unroll
        for (int j = 0; j < 8; ++j)
          acc[i][j] = __builtin_amdgcn_mfma_f32_16x16x32_bf16(af[i], bf[j], acc[i][j], 0, 0, 0);
    }
  }

  float ex[2][8][4];
  float cs[8];
#pragma unroll
  for (int j = 0; j < 8; ++j) cs[j] = 0.f;
#pragma unroll
  for (int i = 0; i < 2; ++i)
#pragma unroll
    for (int j = 0; j < 8; ++j)
#pragma unroll
      for (int rr = 0; rr < 4; ++rr) {
        float l = acc[i][j][rr];
        l = fminf(fmaxf(l, -30.f), 30.f);
        float t = __expf(l);
        ex[i][j][rr] = t;
        cs[j] += t;
      }
#pragma unroll
  for (int j = 0; j < 8; ++j) {
    cs[j] += __shfl_xor(cs[j], 16);
    cs[j] += __shfl_xor(cs[j], 32);
  }
  if (quad == 0) {
#pragma unroll
    for (int j = 0; j < 8; ++j) zs[wave * 128 + j * 16 + l15] = cs[j];
  }
  __syncthreads();

#pragma unroll
  for (int i = 0; i < 2; ++i)
#pragma unroll
    for (int j = 0; j < 8; ++j)
#pragma unroll
      for (int rr = 0; rr < 4; ++rr) {
        int s = wave * 32 + i * 16 + quad * 4 + rr;
        int h = j * 16 + l15;
        sm[s * 128 + (((h >> 3) ^ (s & 15)) * 8) + (h & 7)] = f2bf(ex[i][j][rr]);
      }
  if (tid < 128)
    zpart[mt * 128 + tid] = zs[tid] + zs[128 + tid] + zs[256 + tid] + zs[384 + tid];
  __syncthreads();

  {
    int s = tid >> 1;
#pragma unroll
    for (int i = 0; i < 8; ++i) {
      int c = (tid & 1) * 8 + i;
      s16x8 v = *(const s16x8*)&sm[s * 128 + ((c ^ (s & 15)) * 8)];
      *(s16x8*)(e + (size_t)(rowBase + s) * 128 + c * 8) = v;
    }
  }
  {
    int ck = tid & 15, hb = tid >> 4;
    int b = mt >> 6;
    int sBase = (mt & 63) << 7;
#pragma unroll
    for (int pass = 0; pass < 8; ++pass) {
      int h = hb + pass * 16;
      s16x8 v;
#pragma unroll
      for (int j = 0; j < 8; ++j) {
        int s = ck * 8 + j;
        v[j] = (short)sm[s * 128 + (((h >> 3) ^ (s & 15)) * 8) + (h & 7)];
      }
      *(s16x8*)(eT + (size_t)(b * 128 + h) * 8192 + sBase + ck * 8) = v;
    }
  }
}

// ------------------------------------------------------------------
// k_zmerge: Z per (b,h), store 1/Z^2
__global__ __launch_bounds__(256) void k_zmerge(const float* __restrict__ zpart,
                                                float* __restrict__ rz2) {
  int gid = blockIdx.x * 256 + threadIdx.x;  // 0..1023
  int b = gid >> 7, h = gid & 127;
  float z = 0.f;
  for (int i = 0; i < 64; ++i) z += zpart[(b * 64 + i) * 128 + h];
  rz2[gid] = 1.0f / (z * z);
}

// ------------------------------------------------------------------
// k_E: E^T[c][h] = sum_s x[s][c]*eT[h][s].  x read fp32 DIRECTLY and
// transposed into LDS during staging (no xT pass).  LDS tiles [row][128 s],
// 8-s octets permuted by  pos = oct ^ key(row),  key(r) = ((r>>3)^(r<<1))&15.
// Derived conflict-free for: A-writes (lanes span c>>3), B-writes (lanes
// span octet), both fragment reads (lanes span 16 consecutive rows).
__global__ __launch_bounds__(256) void k_E(const float* __restrict__ x,
                                           const u16* __restrict__ eT,
                                           float* __restrict__ Epart) {
  __shared__ __align__(16) u16 lA[128 * 128];   // [c][s]  32 KiB
  __shared__ __align__(16) u16 lB[128 * 128];   // [h][s]  32 KiB
  const int tid = threadIdx.x;
  const int lane = tid & 63, wave = tid >> 6;
  const int l15 = lane & 15, quad = lane >> 4;
  const int nt = blockIdx.x;   // c band 0..3 (128 wide)
  const int b = blockIdx.y;
  const int kc = blockIdx.z;   // 0..15: 512-s chunk

  f32x4 acc[2][8];
#pragma unroll
  for (int i = 0; i < 2; ++i)
#pragma unroll
    for (int j = 0; j < 8; ++j) acc[i][j] = (f32x4){0.f, 0.f, 0.f, 0.f};

  const int cw = tid & 15, rg = tid >> 4;   // A-stage: c-octet / s-octet owner

  for (int kt = 0; kt < 4; ++kt) {
    const int sb = kc * 512 + kt * 128;
    if (kt) __syncthreads();
    // ---- stage A: x[sb+rg*8+j][nt*128+cw*8+i] -> lA[c][s], transpose in reg
    {
      const float* src = x + ((size_t)(b * 8192 + sb + rg * 8) * 512 + nt * 128 + cw * 8);
      f32x4 v0[8], v1[8];
#pragma unroll
      for (int j = 0; j < 8; ++j) {
        v0[j] = *(const f32x4*)(src + (size_t)j * 512);
        v1[j] = *(const f32x4*)(src + (size_t)j * 512 + 4);
      }
#pragma unroll
      for (int i = 0; i < 8; ++i) {
        const int cl = cw * 8 + i;
        const int key = ((cl >> 3) ^ (cl << 1)) & 15;
        unsigned wv[4];
        if (i < 4) {
          wv[0] = pack2(v0[0][i & 3], v0[1][i & 3]);
          wv[1] = pack2(v0[2][i & 3], v0[3][i & 3]);
          wv[2] = pack2(v0[4][i & 3], v0[5][i & 3]);
          wv[3] = pack2(v0[6][i & 3], v0[7][i & 3]);
        } else {
          wv[0] = pack2(v1[0][i & 3], v1[1][i & 3]);
          wv[1] = pack2(v1[2][i & 3], v1[3][i & 3]);
          wv[2] = pack2(v1[4][i & 3], v1[5][i & 3]);
          wv[3] = pack2(v1[6][i & 3], v1[7][i & 3]);
        }
        *(s16x8*)&lA[cl * 128 + ((rg ^ key) * 8)] = *(const s16x8*)wv;
      }
    }
    // ---- stage B: eT rows (natural k-major), b128 copy
    {
#pragma unroll
      for (int rep = 0; rep < 8; ++rep) {
        const int r = rg + rep * 16;           // h row
        s16x8 v = *(const s16x8*)(eT + (size_t)(b * 128 + r) * 8192 + sb + cw * 8);
        const int key = ((r >> 3) ^ (r << 1)) & 15;
        *(s16x8*)&lB[r * 128 + ((cw ^ key) * 8)] = v;
      }
    }
    __syncthreads();
#pragma unroll
    for (int kk = 0; kk < 4; ++kk) {
      s16x8 af[2], bf[8];
#pragma unroll
      for (int i = 0; i < 2; ++i) {
        const int r = wave * 32 + i * 16 + l15;
        const int key = ((r >> 3) ^ (r << 1)) & 15;
        af[i] = *(const s16x8*)&lA[r * 128 + (((kk * 4 + quad) ^ key) * 8)];
      }
#pragma unroll
      for (int j = 0; j < 8; ++j) {
        const int n = j * 16 + l15;
        const int key = ((n >> 3) ^ (n << 1)) & 15;
        bf[j] = *(const s16x8*)&lB[n * 128 + (((kk * 4 + quad) ^ key) * 8)];
      }
#pragma unroll
      for (int i = 0; i < 2; ++i)
#pragma unroll
        for (int j = 0; j < 8; ++j)
          acc[i][j] = __builtin_amdgcn_mfma_f32_16x16x32_bf16(af[i], bf[j], acc[i][j], 0, 0, 0);
    }
  }
  float* dst = Epart + ((size_t)(kc * 8 + b) * 512 + nt * 128) * 128;
#pragma unroll
  for (int i = 0; i < 2; ++i)
#pragma unroll
    for (int j = 0; j < 8; ++j)
#pragma unroll
      for (int rr = 0; rr < 4; ++rr) {
        int c = wave * 32 + i * 16 + quad * 4 + rr;
        int h = j * 16 + l15;
        dst[(size_t)c * 128 + h] = acc[i][j][rr];
      }
}

// ------------------------------------------------------------------
// k_G: Gt[b][c][h] = bf16( (sum_p Epart[p][b][c][h]) * rz2[b][h] )
__global__ __launch_bounds__(256) void k_G(const float* __restrict__ Epart,
                                           const float* __restrict__ rz2,
                                           u16* __restrict__ Gt) {
  int idx = blockIdx.x * 256 + threadIdx.x;  // 65536 threads, 8 h each
  int h8 = idx & 15, c = (idx >> 4) & 511, b = idx >> 13;
  f32x4 s0 = {0.f, 0.f, 0.f, 0.f}, s1 = {0.f, 0.f, 0.f, 0.f};
#pragma unroll
  for (int p = 0; p < 16; ++p) {
    const float* src = Epart + (((size_t)(p * 8 + b) * 512 + c) * 128 + h8 * 8);
    s0 += *(const f32x4*)src;
    s1 += *(const f32x4*)(src + 4);
  }
  const float* rz = rz2 + b * 128 + h8 * 8;
  f32x4 z0 = *(const f32x4*)rz;
  f32x4 z1 = *(const f32x4*)(rz + 4);
  unsigned ov[4];
  ov[0] = pack2(s0[0] * z0[0], s0[1] * z0[1]);
  ov[1] = pack2(s0[2] * z0[2], s0[3] * z0[3]);
  ov[2] = pack2(s1[0] * z1[0], s1[1] * z1[1]);
  ov[3] = pack2(s1[2] * z1[2], s1[3] * z1[3]);
  *(s16x8*)(Gt + ((size_t)(b * 512 + c) * 128 + h8 * 8)) = *(s16x8*)ov;
}

// ------------------------------------------------------------------
// k_out: out[s][c] = e[s][:] @ G[:, c]  (A = e natural, B = Gt natural)
// [unchanged — verified]
__global__ __launch_bounds__(256) void k_out(const u16* __restrict__ e,
                                             const u16* __restrict__ Gt,
                                             float* __restrict__ out) {
  __shared__ __align__(16) u16 lA[128 * 128];
  __shared__ __align__(16) u16 lB[128 * 128];
  const int tid = threadIdx.x;
  const int lane = tid & 63, wave = tid >> 6;
  const int l15 = lane & 15, quad = lane >> 4;
  const int st = blockIdx.x;
  const int b = blockIdx.y;

  {
    const int hx = tid & 15, rb = tid >> 4;
#pragma unroll
    for (int pass = 0; pass < 8; ++pass) {
      const int r = rb + pass * 16;
      s16x8 v = *(const s16x8*)(e + (size_t)(b * 8192 + st * 128 + r) * 128 + hx * 8);
      *(s16x8*)&lA[r * 128 + ((hx ^ (r & 15)) * 8)] = v;
    }
  }
  for (int ct = 0; ct < 4; ++ct) {
    __syncthreads();
    {
      const int hx = tid & 15, rb = tid >> 4;
#pragma unroll
      for (int pass = 0; pass < 8; ++pass) {
        const int r = rb + pass * 16;
        s16x8 v = *(const s16x8*)(Gt + (size_t)(b * 512 + ct * 128 + r) * 128 + hx * 8);
        *(s16x8*)&lB[r * 128 + ((hx ^ (r & 15)) * 8)] = v;
      }
    }
    __syncthreads();
    f32x4 acc[2][8];
#pragma unroll
    for (int i = 0; i < 2; ++i)
#pragma unroll
      for (int j = 0; j < 8; ++j) acc[i][j] = (f32x4){0.f, 0.f, 0.f, 0.f};
#pragma unroll
    for (int kk = 0; kk < 4; ++kk) {
      s16x8 af[2], bf[8];
#pragma unroll
      for (int i = 0; i < 2; ++i) {
        const int r = wave * 32 + i * 16 + l15;
        af[i] = *(const s16x8*)&lA[r * 128 + (((kk * 4 + quad) ^ (r & 15)) * 8)];
      }
#pragma unroll
      for (int j = 0; j < 8; ++j) {
        const int n = j * 16 + l15;
        bf[j] = *(const s16x8*)&lB[n * 128 + (((kk * 4 + quad) ^ (n & 15)) * 8)];
      }
#pragma unroll
      for (int i = 0; i < 2; ++i)
#pragma unroll
        for (int j = 0; j < 8; ++j)
          acc[i][j] = __builtin_amdgcn_mfma_f32_16x16x32_bf16(af[i], bf[j], acc[i][j], 0, 0, 0);
    }
#pragma unroll
    for (int i = 0; i < 2; ++i)
#pragma unroll
      for (int j = 0; j < 8; ++j)
#pragma unroll
        for (int rr = 0; rr < 4; ++rr) {
          int s = wave * 32 + i * 16 + quad * 4 + rr;
          int c = j * 16 + l15;
          out[(size_t)(b * 8192 + st * 128 + s) * 512 + ct * 128 + c] = acc[i][j][rr];
        }
  }
}

// ------------------------------------------------------------------
extern "C" void kernel_launch(void* const* d_in, const int* in_sizes, int n_in,
                              void* d_out, int out_size, void* d_ws, size_t ws_size,
                              hipStream_t stream) {
  if (ws_size < (size_t)WS_NEED) return;  // need ~65.4 MiB scratch
  const float* x = (const float*)d_in[0];
  const float* W = (const float*)d_in[1];
  float* out = (float*)d_out;
  char* ws = (char*)d_ws;
  u16* e = (u16*)(ws + OFF_E);
  u16* eT = (u16*)(ws + OFF_ET);
  float* Epart = (float*)(ws + OFF_EPART);
  u16* Gt = (u16*)(ws + OFF_GT);
  u16* Wt = (u16*)(ws + OFF_WT);
  float* zpart = (float*)(ws + OFF_ZP);
  float* rz2 = (float*)(ws + OFF_RZ2);

  k_wt<<<256, 256, 0, stream>>>(W, Wt);
  k_logits_e<<<512, 256, 0, stream>>>(x, Wt, e, eT, zpart);
  k_zmerge<<<4, 256, 0, stream>>>(zpart, rz2);
  k_E<<<dim3(4, 8, 16), 256, 0, stream>>>(x, eT, Epart);
  k_G<<<256, 256, 0, stream>>>(Epart, rz2, Gt);
  k_out<<<dim3(64, 8), 256, 0, stream>>>(e, Gt, out);
}